// Round 5
// baseline (338.381 us; speedup 1.0000x reference)
//
#include <hip/hip_runtime.h>
#include <stdint.h>

#define GENOMES 8
#define BATCH 2
#define SEQ 2048
#define EMBED 1024
#define KVD 256              // KV_HEADS * HEAD_DIM
#define M_PER_G (BATCH*SEQ)  // 4096

typedef float f32x4 __attribute__((ext_vector_type(4)));
typedef __bf16 bf16x8 __attribute__((ext_vector_type(8)));
typedef short s16x8 __attribute__((ext_vector_type(8)));
typedef short s16x4 __attribute__((ext_vector_type(4)));

static __device__ __forceinline__ unsigned short f2bf(float f) {
  unsigned int u = __builtin_bit_cast(unsigned int, f);
  u += 0x7FFFu + ((u >> 16) & 1u);   // round-to-nearest-even
  return (unsigned short)(u >> 16);
}

// lgkm-only drain + workgroup barrier (does NOT drain vmcnt: in-flight
// global loads survive the barrier)
#define LGKM_BARRIER() do { \
  asm volatile("s_waitcnt lgkmcnt(0)" ::: "memory"); \
  __builtin_amdgcn_s_barrier(); \
  asm volatile("" ::: "memory"); \
} while (0)

// ---------------------------------------------------------------------------
// Wv (g, 1024, 256) fp32  ->  WvT (g, 256, 1024) bf16   (B^T layout for GEMM1)
// ---------------------------------------------------------------------------
__global__ __launch_bounds__(256) void wvt_kernel(const float* __restrict__ Wv,
                                                  unsigned short* __restrict__ WvT) {
  int g = blockIdx.y;
  int it = blockIdx.x >> 2;          // 16 i-tiles of 64
  int ot = blockIdx.x & 3;           // 4 o-tiles of 64
  int i0 = it * 64, o0 = ot * 64;
  const float* W = Wv + (size_t)g * EMBED * KVD;
  unsigned short* T = WvT + (size_t)g * KVD * EMBED;
  __shared__ unsigned short tl[64][65];
  int t = threadIdx.x;
  int rr = t >> 4;            // 0..15
  int cc = (t & 15) * 4;      // 0..60
#pragma unroll
  for (int p = 0; p < 4; ++p) {
    int r = rr + p * 16;
    float4 v = *(const float4*)(W + (size_t)(i0 + r) * KVD + o0 + cc);
    tl[r][cc + 0] = f2bf(v.x);
    tl[r][cc + 1] = f2bf(v.y);
    tl[r][cc + 2] = f2bf(v.z);
    tl[r][cc + 3] = f2bf(v.w);
  }
  __syncthreads();
#pragma unroll
  for (int p = 0; p < 4; ++p) {
    int o = rr + p * 16;
    s16x4 v;
    v[0] = (short)tl[cc + 0][o];
    v[1] = (short)tl[cc + 1][o];
    v[2] = (short)tl[cc + 2][o];
    v[3] = (short)tl[cc + 3][o];
    *(s16x4*)(T + (size_t)(o0 + o) * EMBED + i0 + cc) = v;
  }
}

// ---------------------------------------------------------------------------
// Wo (g, 1024, 1024) fp32 -> RT (g, 1024, 256) bf16
// RT[o][kh*64+d] = 64 * sum_{r=0..3} Wo[kh*256 + r*64 + d][o]
// (head-broadcast folded into Wo, x64 softmax-sum factor folded in, transposed)
// ---------------------------------------------------------------------------
__global__ __launch_bounds__(256) void rt_kernel(const float* __restrict__ Wo,
                                                 unsigned short* __restrict__ RT) {
  int g = blockIdx.y;
  int ot = blockIdx.x >> 2;          // 16 o-tiles of 64
  int kh = blockIdx.x & 3;           // 4 kv heads
  int o0 = ot * 64;
  const float* W = Wo + (size_t)g * EMBED * EMBED;
  unsigned short* T = RT + (size_t)g * EMBED * KVD;
  __shared__ float tl[64][65];
  int t = threadIdx.x;
  int rr = t >> 4;
  int cc = (t & 15) * 4;
#pragma unroll
  for (int p = 0; p < 4; ++p) {
    int d = rr + p * 16;
    float a0 = 0.f, a1 = 0.f, a2 = 0.f, a3 = 0.f;
#pragma unroll
    for (int r = 0; r < 4; ++r) {
      float4 v = *(const float4*)(W + (size_t)(kh * 256 + r * 64 + d) * EMBED + o0 + cc);
      a0 += v.x; a1 += v.y; a2 += v.z; a3 += v.w;
    }
    tl[d][cc + 0] = a0; tl[d][cc + 1] = a1; tl[d][cc + 2] = a2; tl[d][cc + 3] = a3;
  }
  __syncthreads();
#pragma unroll
  for (int p = 0; p < 4; ++p) {
    int o = rr + p * 16;
    s16x4 v;
    v[0] = (short)f2bf(64.f * tl[cc + 0][o]);
    v[1] = (short)f2bf(64.f * tl[cc + 1][o]);
    v[2] = (short)f2bf(64.f * tl[cc + 2][o]);
    v[3] = (short)f2bf(64.f * tl[cc + 3][o]);
    *(s16x4*)(T + (size_t)(o0 + o) * KVD + kh * 64 + cc) = v;
  }
}

// ---------------------------------------------------------------------------
// C[M,N] = A[M,K] * Bt[N,K]^T   (per genome in blockIdx.y)
// BM=64, BN=256, BK=32. 256 threads = 4 waves; each wave computes the full
// 64 M-rows x its own 64 N-cols (acc[4][4], 16 MFMA/iter).
//
// KEY CHANGE vs R4: B is NEVER staged in LDS. B-fragments (row of B^T,
// 8 contiguous k) are loaded per-lane straight from global (L2-resident
// weights), double-buffered in registers. Only A goes through LDS --
// reg-staged (f32->bf16 converted at stage time), 4 KB/iter, double-
// buffered, one lgkm-only barrier per iter (in-flight vmem survives).
// This sidesteps the ~16-23 B/cyc/CU global_load_lds staging ceiling that
// pinned every previous round at ~80 us.
// ---------------------------------------------------------------------------
template <bool A_F32, bool OUT_BF16, int M, int N, int K>
__global__ __launch_bounds__(256) void gemm_bt(const void* __restrict__ Aall,
                                               const unsigned short* __restrict__ Btall,
                                               void* __restrict__ Call) {
  constexpr int BM = 64, BN = 256, BK = 32;
  constexpr int NTN = N / BN;
  constexpr int NWG = (M / BM) * NTN;
  constexpr int NT = K / BK;                 // 32 (GEMM1) or 8 (GEMM2)
  static_assert(NWG % 8 == 0, "XCD swizzle needs nwg%8==0");
  static_assert(NT % 2 == 0 && NT >= 4, "manual 2-unroll + 2-ahead A prefetch");

  __shared__ __align__(16) unsigned char As[2][BM * BK * 2];   // 2 x 4 KB bf16

  int g = blockIdx.y;
  int bid = blockIdx.x;
  // bijective XCD swizzle: contiguous chunk of m-tiles per XCD.
  int lt = (bid & 7) * (NWG >> 3) + (bid >> 3);
  int bm = lt / NTN, bn = lt % NTN;
  int m0 = bm * BM, n0 = bn * BN;

  const unsigned short* Bt = Btall + (size_t)g * N * K;
  const float* Af = (const float*)Aall + (size_t)g * M * K;
  const unsigned short* Ab = (const unsigned short*)Aall + (size_t)g * M * K;

  int tid = threadIdx.x;
  int lane = tid & 63, wave = tid >> 6;
  int lm = lane & 15, quad = lane >> 4;
  int wn = wave * 64;                        // wave's N-quadrant

  // ---- A staging mapping (reg -> LDS, swizzled at write time) ----
  // LDS row = 64 B (32 bf16), 4 granules of 16B; granule c stored at c^(row&3).
  int srow = tid >> 2, sc4 = tid & 3;        // 64 rows x 4 granule-threads
  int sdst = srow * 64 + ((sc4 ^ (srow & 3)) * 16);
  const float* gAf = Af + (size_t)(m0 + srow) * K + sc4 * 8;
  const unsigned short* gAb = Ab + (size_t)(m0 + srow) * K + sc4 * 8;

  // ---- A fragment read offsets (swizzled) ----
  int offA[4];
#pragma unroll
  for (int i = 0; i < 4; ++i) {
    int row = i * 16 + lm;
    offA[i] = row * 64 + ((quad ^ (row & 3)) * 16);
  }

  // ---- B fragment global pointers (per-lane, direct from L2) ----
  const unsigned short* gB[4];
#pragma unroll
  for (int j = 0; j < 4; ++j)
    gB[j] = Bt + (size_t)(n0 + wn + j * 16 + lm) * K + quad * 8;

  f32x4 acc[4][4] = {};

  // register double-buffers (all statically indexed -- rule #20)
  bf16x8 b0[4], b1[4];
  f32x4 a0l, a0h, a1l, a1h;   // A f32 path
  s16x8 a0b, a1b;             // A bf16 path

  auto loadA = [&](int h, f32x4& dl, f32x4& dh, s16x8& db) {
    if constexpr (A_F32) {
      const float* s = gAf + (size_t)h * BK;
      dl = *(const f32x4*)(s);
      dh = *(const f32x4*)(s + 4);
    } else {
      db = *(const s16x8*)(gAb + (size_t)h * BK);
    }
  };
  auto writeA = [&](int h, const f32x4& sl, const f32x4& sh, const s16x8& sb) {
    s16x8 w;
    if constexpr (A_F32) {
#pragma unroll
      for (int u = 0; u < 4; ++u) {
        w[u] = (short)f2bf(sl[u]);
        w[4 + u] = (short)f2bf(sh[u]);
      }
    } else {
      w = sb;
    }
    *(s16x8*)(&As[h & 1][sdst]) = w;
  };
  auto loadB = [&](int h, bf16x8 (&dst)[4]) {
#pragma unroll
    for (int j = 0; j < 4; ++j)
      dst[j] = __builtin_bit_cast(bf16x8, *(const s16x8*)(gB[j] + (size_t)h * BK));
  };

  // body(h): MFMA on A(h)[LDS] x B(h)[bcur]; prefetch B(h+1)->bnxt,
  // A(h+2)->(dl,dh,db); write A(h+1) from (sl,sh,sb) to slot (h+1)&1
  // (that slot was last read at iter h-1, before the previous barrier).
  auto body = [&](int h, bf16x8 (&bcur)[4], bf16x8 (&bnxt)[4],
                  f32x4& dl, f32x4& dh, s16x8& db,
                  f32x4& sl, f32x4& sh, s16x8& sb) {
    if (h + 1 < NT) loadB(h + 1, bnxt);
    if (h + 2 < NT) loadA(h + 2, dl, dh, db);

    const unsigned char* base = &As[h & 1][0];
    bf16x8 a[4];
#pragma unroll
    for (int i = 0; i < 4; ++i)
      a[i] = __builtin_bit_cast(bf16x8, *(const s16x8*)(base + offA[i]));

#pragma unroll
    for (int i = 0; i < 4; ++i)
#pragma unroll
      for (int j = 0; j < 4; ++j)
        acc[i][j] = __builtin_amdgcn_mfma_f32_16x16x32_bf16(a[i], bcur[j], acc[i][j], 0, 0, 0);

    if (h + 1 < NT) writeA(h + 1, sl, sh, sb);
    LGKM_BARRIER();
  };

  // ---- prologue: A(0),A(1) to regs; A(0) -> LDS slot0; B(0) -> b0 ----
  loadA(0, a0l, a0h, a0b);
  loadA(1, a1l, a1h, a1b);
  writeA(0, a0l, a0h, a0b);
  loadB(0, b0);
  LGKM_BARRIER();

  for (int h = 0; h < NT; h += 2) {
    body(h,     b0, b1, a0l, a0h, a0b, a1l, a1h, a1b);  // A(h+2)->a0, write A(h+1) from a1
    body(h + 1, b1, b0, a1l, a1h, a1b, a0l, a0h, a0b);  // A(h+3)->a1, write A(h+2) from a0
  }

  // ---- epilogue: C/D layout col=lane&15, row=quad*4+reg ----
  if constexpr (OUT_BF16) {
    unsigned short* C = (unsigned short*)Call + (size_t)g * M * N;
#pragma unroll
    for (int i = 0; i < 4; ++i)
#pragma unroll
      for (int j = 0; j < 4; ++j)
#pragma unroll
        for (int r = 0; r < 4; ++r) {
          int mm = m0 + i * 16 + quad * 4 + r;
          int nn = n0 + wn + j * 16 + lm;
          C[(size_t)mm * N + nn] = f2bf(acc[i][j][r]);
        }
  } else {
    float* C = (float*)Call + (size_t)g * M * N;
#pragma unroll
    for (int i = 0; i < 4; ++i)
#pragma unroll
      for (int j = 0; j < 4; ++j)
#pragma unroll
        for (int r = 0; r < 4; ++r) {
          int mm = m0 + i * 16 + quad * 4 + r;
          int nn = n0 + wn + j * 16 + lm;
          C[(size_t)mm * N + nn] = acc[i][j][r];
        }
  }
}

// ---------------------------------------------------------------------------
extern "C" void kernel_launch(void* const* d_in, const int* in_sizes, int n_in,
                              void* d_out, int out_size, void* d_ws, size_t ws_size,
                              hipStream_t stream) {
  const float* tensor = (const float*)d_in[0];
  // d_in[1] = Wq, d_in[2] = Wk: dead code in the reference (the buggy einsum
  // contracts them out; softmax collapses to a uniform x64 factor)
  const float* Wv = (const float*)d_in[3];
  const float* Wo = (const float*)d_in[4];
  float* out = (float*)d_out;

  unsigned short* WvT = (unsigned short*)d_ws;                       //  4 MB
  unsigned short* RT  = WvT + (size_t)GENOMES * KVD * EMBED;         //  4 MB
  unsigned short* V   = RT  + (size_t)GENOMES * EMBED * KVD;         // 16 MB

  // prep: transpose/convert Wv, fold+transpose/convert Wo
  wvt_kernel<<<dim3(64, GENOMES), 256, 0, stream>>>(Wv, WvT);
  rt_kernel<<<dim3(64, GENOMES), 256, 0, stream>>>(Wo, RT);

  // GEMM1: V[g] (4096x256 bf16) = tensor[g] (4096x1024 f32->bf16) @ WvT^T
  gemm_bt<true, true, M_PER_G, KVD, EMBED>
      <<<dim3((M_PER_G / 64) * (KVD / 256), GENOMES), 256, 0, stream>>>(tensor, WvT, V);

  // GEMM2: out[g] (4096x1024 f32) = V[g] (4096x256 bf16) @ RT^T  (x64 folded in RT)
  gemm_bt<false, false, M_PER_G, EMBED, KVD>
      <<<dim3((M_PER_G / 64) * (EMBED / 256), GENOMES), 256, 0, stream>>>(V, RT, out);
}